// Round 1
// baseline (2411.507 us; speedup 1.0000x reference)
//
#include <hip/hip_runtime.h>

// Problem constants (from reference)
#define NB   32
#define CH   2
#define HH   640
#define WW   640
#define HW   (HH * WW)        // 409600 pixels per image
#define NHW  (NB * HW)        // 13107200 pixels total
#define PLANE (CH * HW)       // 819200 floats per image, planar
#define HALF (NB * PLANE)     // 26214400 floats per output tensor

// K0: v [N,2,H,W] planar -> disp0 interleaved [N,H,W,2], scaled by 2^-32
__global__ void k_init(const float* __restrict__ v, float2* __restrict__ out) {
    int idx = blockIdx.x * blockDim.x + threadIdx.x;
    if (idx >= NHW) return;
    int n = idx / HW;
    int p = idx - n * HW;
    const float s = 2.3283064365386963e-10f;  // 2^-32, exact
    float dx = v[n * PLANE + p] * s;
    float dy = v[n * PLANE + HW + p] * s;
    out[idx] = make_float2(dx, dy);
}

// One scaling-and-squaring step:
//   out(x) = in(x) + bilinear_sample_border(in, identity(x) + in(x))
// in/out interleaved [N,H,W,2]; ig is identity grid [H,W,2] (x then y, in [-1,1])
__global__ void k_step(const float2* __restrict__ in,
                       const float2* __restrict__ ig,
                       float2* __restrict__ out) {
    int idx = blockIdx.x * blockDim.x + threadIdx.x;
    if (idx >= NHW) return;
    int n = idx / HW;
    int p = idx - n * HW;

    const float2* img = in + (size_t)n * HW;
    float2 d = img[p];
    float2 g = ig[p];

    // normalized sample coords
    float gx = g.x + d.x;
    float gy = g.y + d.y;

    // unnormalize (align_corners=True) + border clamp
    float fx = (gx + 1.0f) * (0.5f * (float)(WW - 1));
    float fy = (gy + 1.0f) * (0.5f * (float)(HH - 1));
    fx = fminf(fmaxf(fx, 0.0f), (float)(WW - 1));
    fy = fminf(fmaxf(fy, 0.0f), (float)(HH - 1));

    float x0f = floorf(fx);
    float y0f = floorf(fy);
    int x0 = (int)x0f;
    int y0 = (int)y0f;
    int x1 = min(x0 + 1, WW - 1);
    int y1 = min(y0 + 1, HH - 1);
    float wx = fx - x0f;
    float wy = fy - y0f;
    float omwx = 1.0f - wx;
    float omwy = 1.0f - wy;

    float2 v00 = img[y0 * WW + x0];
    float2 v01 = img[y0 * WW + x1];
    float2 v10 = img[y1 * WW + x0];
    float2 v11 = img[y1 * WW + x1];

    float topx = v00.x * omwx + v01.x * wx;
    float topy = v00.y * omwx + v01.y * wx;
    float botx = v10.x * omwx + v11.x * wx;
    float boty = v10.y * omwx + v11.y * wx;
    float sx = topx * omwy + botx * wy;
    float sy = topy * omwy + boty * wy;

    out[idx] = make_float2(d.x + sx, d.y + sy);
}

// F1: interleaved [N,H,W,2] -> planar displacement [N,2,H,W]
__global__ void k_deinterleave(const float2* __restrict__ in, float* __restrict__ disp) {
    int idx = blockIdx.x * blockDim.x + threadIdx.x;
    if (idx >= NHW) return;
    int n = idx / HW;
    int p = idx - n * HW;
    float2 d = in[idx];
    disp[n * PLANE + p]      = d.x;
    disp[n * PLANE + HW + p] = d.y;
}

// F2: transformation[n,c,y,x] = identity[y,x,c] + disp[n,c,y,x]
__global__ void k_trans(const float* __restrict__ disp,
                        const float* __restrict__ ig,
                        float* __restrict__ trans) {
    int idx = blockIdx.x * blockDim.x + threadIdx.x;
    if (idx >= HALF) return;
    int r = idx % PLANE;          // within-image planar offset
    int c = r / HW;               // channel 0=x, 1=y
    int p = r - c * HW;           // pixel
    trans[idx] = disp[idx] + ig[p * 2 + c];
}

extern "C" void kernel_launch(void* const* d_in, const int* in_sizes, int n_in,
                              void* d_out, int out_size, void* d_ws, size_t ws_size,
                              hipStream_t stream) {
    const float*  v  = (const float*)d_in[0];
    const float2* ig = (const float2*)d_in[1];
    float* out = (float*)d_out;

    // Ping-pong interleaved disp buffers inside d_out (each half = NHW float2)
    float2* h0 = (float2*)out;           // half 0 (transformation slot)
    float2* h1 = (float2*)(out + HALF);  // half 1 (displacement slot)
    float2* bufs[2] = { h0, h1 };

    const int threads = 256;
    const int blocks  = (NHW + threads - 1) / threads;

    // disp0 -> h0
    k_init<<<blocks, threads, 0, stream>>>(v, h0);

    // 32 squaring steps; step i reads bufs[(i-1)&1], writes bufs[i&1].
    // disp32 ends in bufs[0] = h0.
    for (int i = 1; i <= 32; ++i) {
        k_step<<<blocks, threads, 0, stream>>>(bufs[(i - 1) & 1], ig, bufs[i & 1]);
    }

    // displacement (planar) into second half
    k_deinterleave<<<blocks, threads, 0, stream>>>(h0, out + HALF);

    // transformation (planar) into first half
    const int blocks2 = (HALF + threads - 1) / threads;
    k_trans<<<blocks2, threads, 0, stream>>>(out + HALF, (const float*)d_in[1], out);
}

// Round 4
// 1959.397 us; speedup vs baseline: 1.2307x; 1.2307x over previous
//
#include <hip/hip_runtime.h>
#include <utility>

// Problem constants (from reference)
#define NB   32
#define CH   2
#define HH   640
#define WW   640
#define HW   (HH * WW)        // 409600 pixels per image
#define NHW  (NB * HW)        // 13107200 pixels total
#define PLANE (CH * HW)       // 819200 floats per image, planar
#define HALF (NB * PLANE)     // 26214400 floats per output tensor

#define BLK_PX       512                   // pixels per block (256 thr x 2 px)
#define BLKS_PER_IMG (HW / BLK_PX)         // 800
#define GRID_STEP    (NB * BLKS_PER_IMG)   // 25600

// K0: v [N,2,H,W] planar -> disp0 interleaved [N,H,W,2], scaled by 2^-32
__global__ void k_init(const float* __restrict__ v, float2* __restrict__ out) {
    int idx = blockIdx.x * blockDim.x + threadIdx.x;
    if (idx >= NHW) return;
    int n = idx / HW;
    int p = idx - n * HW;
    const float s = 2.3283064365386963e-10f;  // 2^-32, exact
    float dx = v[n * PLANE + p] * s;
    float dy = v[n * PLANE + HW + p] * s;
    out[idx] = make_float2(dx, dy);
}

// Bilinear sample with border clamp, align_corners=True. img interleaved [H,W,2].
__device__ __forceinline__ float2 bilin_sample(const float2* __restrict__ img,
                                               float gx, float gy) {
    float fx = (gx + 1.0f) * (0.5f * (float)(WW - 1));
    float fy = (gy + 1.0f) * (0.5f * (float)(HH - 1));
    fx = fminf(fmaxf(fx, 0.0f), (float)(WW - 1));
    fy = fminf(fmaxf(fy, 0.0f), (float)(HH - 1));
    float x0f = floorf(fx);
    float y0f = floorf(fy);
    int x0 = (int)x0f;
    int y0 = (int)y0f;
    int x1 = min(x0 + 1, WW - 1);
    int y1 = min(y0 + 1, HH - 1);
    float wx = fx - x0f;
    float wy = fy - y0f;
    float omwx = 1.0f - wx;
    float omwy = 1.0f - wy;
    float2 v00 = img[y0 * WW + x0];
    float2 v01 = img[y0 * WW + x1];
    float2 v10 = img[y1 * WW + x0];
    float2 v11 = img[y1 * WW + x1];
    float topx = v00.x * omwx + v01.x * wx;
    float topy = v00.y * omwx + v01.y * wx;
    float botx = v10.x * omwx + v11.x * wx;
    float boty = v10.y * omwx + v11.y * wx;
    return make_float2(topx * omwy + botx * wy, topy * omwy + boty * wy);
}

// One squaring step, 2 px/thread, XCD-pinned: image n -> XCD n%8 (blockIdx%8
// round-robin heuristic); pure index permutation, semantically inert.
// STEP is only a symbol tag so rocprof separates the 32 dispatches.
template<int STEP>
__global__ __launch_bounds__(256) void k_step(const float2* __restrict__ in,
                                              const float2* __restrict__ ig,
                                              float2* __restrict__ out) {
    int b = blockIdx.x;
    int xcd = b & 7;
    int slot = b >> 3;                   // 0..3199
    int img_round = slot / BLKS_PER_IMG; // 0..3
    int blk = slot - img_round * BLKS_PER_IMG;
    int n = img_round * 8 + xcd;         // image -> fixed XCD
    int q = blk * (BLK_PX / 2) + threadIdx.x;   // float4 (pixel-pair) index in image

    const float2* img  = in + (size_t)n * HW;
    const float4* img4 = (const float4*)img;
    const float4* ig4  = (const float4*)ig;
    float4 d = img4[q];
    float4 g = ig4[q];

    float2 s0 = bilin_sample(img, g.x + d.x, g.y + d.y);
    float2 s1 = bilin_sample(img, g.z + d.z, g.w + d.w);

    float4 o = make_float4(d.x + s0.x, d.y + s0.y, d.z + s1.x, d.w + s1.y);
    float4* out4 = (float4*)(out + (size_t)n * HW);
    out4[q] = o;
}

// F1: interleaved [N,H,W,2] (h0) -> planar displacement [N,2,H,W] (h1)
__global__ __launch_bounds__(256) void k_deinterleave(const float2* __restrict__ in,
                                                      float* __restrict__ disp) {
    int i = blockIdx.x * blockDim.x + threadIdx.x;  // pixel-pair index
    if (i >= NHW / 2) return;
    int n = i / (HW / 2);
    int qp = i - n * (HW / 2);
    int p = qp * 2;
    const float4* in4 = (const float4*)(in + (size_t)n * HW);
    float4 d = in4[qp];
    float* dispn = disp + (size_t)n * PLANE;
    *(float2*)(dispn + p)      = make_float2(d.x, d.z);
    *(float2*)(dispn + HW + p) = make_float2(d.y, d.w);
}

// F2: transformation[n,c,y,x] = identity[y,x,c] + disp[n,c,y,x]  (h1 -> h0)
__global__ __launch_bounds__(256) void k_trans(const float* __restrict__ disp,
                                               const float2* __restrict__ ig,
                                               float* __restrict__ trans) {
    int i = blockIdx.x * blockDim.x + threadIdx.x;  // pixel-pair index
    if (i >= NHW / 2) return;
    int n = i / (HW / 2);
    int qp = i - n * (HW / 2);
    int p = qp * 2;
    const float4* ig4 = (const float4*)ig;
    float4 g = ig4[qp];  // (x0,y0,x1,y1) of pixels p, p+1
    const float* dispn = disp + (size_t)n * PLANE;
    float* transn = trans + (size_t)n * PLANE;
    float2 dx = *(const float2*)(dispn + p);
    float2 dy = *(const float2*)(dispn + HW + p);
    *(float2*)(transn + p)      = make_float2(dx.x + g.x, dx.y + g.z);
    *(float2*)(transn + HW + p) = make_float2(dy.x + g.y, dy.y + g.w);
}

// Launch step I (1..32): odd steps read h0 write h1, even read h1 write h0.
// disp32 ends in h0.
template<int I>
static inline void launch_step(float2* h0, float2* h1, const float2* ig, hipStream_t s) {
    const float2* src = (I & 1) ? (const float2*)h0 : (const float2*)h1;
    float2* dst       = (I & 1) ? h1 : h0;
    k_step<I><<<GRID_STEP, 256, 0, s>>>(src, ig, dst);
}

template<int... Is>
static inline void launch_all(std::integer_sequence<int, Is...>,
                              float2* h0, float2* h1, const float2* ig, hipStream_t s) {
    (launch_step<Is + 1>(h0, h1, ig, s), ...);
}

extern "C" void kernel_launch(void* const* d_in, const int* in_sizes, int n_in,
                              void* d_out, int out_size, void* d_ws, size_t ws_size,
                              hipStream_t stream) {
    const float*  v  = (const float*)d_in[0];
    const float2* ig = (const float2*)d_in[1];
    float* out = (float*)d_out;

    float2* h0 = (float2*)out;           // transformation slot (ping)
    float2* h1 = (float2*)(out + HALF);  // displacement slot (pong)

    const int threads = 256;
    const int blocks  = (NHW + threads - 1) / threads;

    // disp0 -> h0
    k_init<<<blocks, threads, 0, stream>>>(v, h0);

    // 32 squaring steps; disp32 ends in h0.
    launch_all(std::make_integer_sequence<int, 32>{}, h0, h1, ig, stream);

    // displacement (planar) h0 -> h1
    const int blocks2 = (NHW / 2 + threads - 1) / threads;
    k_deinterleave<<<blocks2, threads, 0, stream>>>(h0, out + HALF);

    // transformation (planar) h1 -> h0
    k_trans<<<blocks2, threads, 0, stream>>>(out + HALF, ig, out);
}